// Round 3
// baseline (3712.773 us; speedup 1.0000x reference)
//
#include <hip/hip_runtime.h>
#include <hip/hip_bf16.h>

// Problem constants
constexpr int B_ = 2, S_ = 1024, H_ = 2048;
constexpr int NH_ = 16, NKV_ = 8, HD_ = 128, GROUPS_ = 2;
constexpr int TOPK_ = 409;  // int(0.4 * 1024)
constexpr int QSTRIDE = NH_ * HD_;   // 2048
constexpr int KSTRIDE = NKV_ * HD_;  // 1024

__device__ inline unsigned fkey(float x) {
  unsigned u = __float_as_uint(x);
  return (u & 0x80000000u) ? ~u : (u | 0x80000000u);
}

// ---------------------------------------------------------------------------
// Tiled GEMM: C[m,n] = sum_k A[m,k] * W[n,k] + bias[n]   (all fp32)
// A: [M x K] row-major, W: [N x K] row-major, C: [M x N]
// block 256 threads, 64x64 tile, 4x4 per thread, BK=16. All dims divide evenly.
// ---------------------------------------------------------------------------
__global__ __launch_bounds__(256) void gemm_bias(
    const float* __restrict__ A, const float* __restrict__ W,
    const float* __restrict__ bias, float* __restrict__ C, int N, int K) {
  __shared__ float As[16][65];
  __shared__ float Bs[16][65];
  const int tid = threadIdx.x;
  const int tx = tid & 15, ty = tid >> 4;
  const int m0 = blockIdx.y * 64, n0 = blockIdx.x * 64;
  float acc[4][4] = {};
  for (int k0 = 0; k0 < K; k0 += 16) {
#pragma unroll
    for (int l = 0; l < 4; ++l) {
      int idx = tid + l * 256;  // 0..1023
      int m = idx >> 4, kk = idx & 15;
      As[kk][m] = A[(size_t)(m0 + m) * K + k0 + kk];
      Bs[kk][m] = W[(size_t)(n0 + m) * K + k0 + kk];
    }
    __syncthreads();
#pragma unroll
    for (int kk = 0; kk < 16; ++kk) {
      float a[4], bb[4];
#pragma unroll
      for (int i = 0; i < 4; ++i) a[i] = As[kk][ty * 4 + i];
#pragma unroll
      for (int j = 0; j < 4; ++j) bb[j] = Bs[kk][tx * 4 + j];
#pragma unroll
      for (int i = 0; i < 4; ++i)
#pragma unroll
        for (int j = 0; j < 4; ++j) acc[i][j] += a[i] * bb[j];
    }
    __syncthreads();
  }
#pragma unroll
  for (int i = 0; i < 4; ++i) {
    int m = m0 + ty * 4 + i;
#pragma unroll
    for (int j = 0; j < 4; ++j) {
      int n = n0 + tx * 4 + j;
      C[(size_t)m * N + n] = acc[i][j] + bias[n];
    }
  }
}

// ---------------------------------------------------------------------------
// In-place RoPE on qtmp [token, NH*HD] and ktmp [token, NKV*HD].
// grid: (S, NH+NKV, B), block: 64 (thread d handles the pair d, d+64)
// ---------------------------------------------------------------------------
__global__ __launch_bounds__(64) void rope_inplace(
    float* __restrict__ qtmp, float* __restrict__ ktmp,
    const int* __restrict__ pos_ids) {
  const int s = blockIdx.x;
  const int hh = blockIdx.y;
  const int b = blockIdx.z;
  const int d = threadIdx.x;  // 0..63
  const int pos = pos_ids[b * S_ + s];
  float* ptr;
  if (hh < NH_) {
    ptr = qtmp + (size_t)(b * S_ + s) * QSTRIDE + hh * HD_;
  } else {
    ptr = ktmp + (size_t)(b * S_ + s) * KSTRIDE + (hh - NH_) * HD_;
  }
  float x = ptr[d], y = ptr[d + 64];
  float f = (float)(1.0 / pow(1.0e6, (double)d / 64.0));
  float ang = (float)pos * f;
  float c = cosf(ang), sn = sinf(ang);
  ptr[d] = x * c - y * sn;
  ptr[d + 64] = y * c + x * sn;
}

// ---------------------------------------------------------------------------
// Sparse attention, one block (256 thr) per (b, h, query) row.
// Reads Q/K/V from the [token, head*HD] projection buffers, writes the
// attention output in place over this block's own Q segment.
// scores -> exact 409th-largest via 4-pass radix select -> masked softmax -> PV
// ---------------------------------------------------------------------------
__global__ __launch_bounds__(256) void attn_kernel(
    float* __restrict__ qtmp, const float* __restrict__ ktmp,
    const float* __restrict__ vtmp) {
  const int qs = blockIdx.x;
  const int h = blockIdx.y;
  const int b = blockIdx.z;
  const int g = h / GROUPS_;
  const int t = threadIdx.x;
  __shared__ float qrow[HD_];
  __shared__ float sc[S_];
  __shared__ unsigned keys[S_];
  __shared__ unsigned hist[256];
  __shared__ float red[256];
  __shared__ int sh_bin;
  const float scale = 0.08838834764831845f;  // 1/sqrt(128)

  float* qseg = qtmp + (size_t)(b * S_ + qs) * QSTRIDE + h * HD_;
  if (t < HD_) qrow[t] = qseg[t];
  __syncthreads();

#pragma unroll
  for (int r = 0; r < 4; ++r) {
    int i = t + r * 256;
    const float4* k4 =
        (const float4*)(ktmp + (size_t)(b * S_ + i) * KSTRIDE + g * HD_);
    float acc = 0.f;
#pragma unroll 8
    for (int d4 = 0; d4 < 32; ++d4) {
      float4 kv = k4[d4];
      acc += qrow[d4 * 4 + 0] * kv.x + qrow[d4 * 4 + 1] * kv.y +
             qrow[d4 * 4 + 2] * kv.z + qrow[d4 * 4 + 3] * kv.w;
    }
    float sval = acc * scale;
    sc[i] = sval;
    keys[i] = fkey(sval);
  }
  __syncthreads();

  // radix select: exact key of the TOPK_-th largest
  int kk = TOPK_;
  unsigned prefix = 0;
  for (int pass = 0; pass < 4; ++pass) {
    const int shift = 24 - 8 * pass;
    const unsigned pmask = pass ? (0xFFFFFFFFu << (shift + 8)) : 0u;
    hist[t] = 0;
    __syncthreads();
#pragma unroll
    for (int r = 0; r < 4; ++r) {
      unsigned u = keys[t + r * 256];
      if ((u & pmask) == (prefix & pmask))
        atomicAdd(&hist[(u >> shift) & 0xFF], 1u);
    }
    __syncthreads();
    // in-place suffix sum: hist[i] = count of candidates with digit >= i
    for (int off = 1; off < 256; off <<= 1) {
      unsigned vv = (t + off < 256) ? hist[t + off] : 0u;
      __syncthreads();
      hist[t] += vv;
      __syncthreads();
    }
    unsigned self = hist[t];
    unsigned above = (t == 255) ? 0u : hist[t + 1];
    if (self >= (unsigned)kk && above < (unsigned)kk) sh_bin = t;
    __syncthreads();
    int bb = sh_bin;
    unsigned above_cnt = (bb == 255) ? 0u : hist[bb + 1];
    kk -= (int)above_cnt;
    prefix |= ((unsigned)bb) << shift;
    __syncthreads();
  }

  // masked softmax (global max is always kept since its key >= prefix)
  float mloc = -1e30f;
#pragma unroll
  for (int r = 0; r < 4; ++r) mloc = fmaxf(mloc, sc[t + r * 256]);
  red[t] = mloc;
  __syncthreads();
  for (int off = 128; off > 0; off >>= 1) {
    if (t < off) red[t] = fmaxf(red[t], red[t + off]);
    __syncthreads();
  }
  float mx = red[0];
  __syncthreads();

  float zloc = 0.f;
#pragma unroll
  for (int r = 0; r < 4; ++r) {
    int i = t + r * 256;
    float p = (keys[i] >= prefix) ? expf(sc[i] - mx) : 0.0f;
    sc[i] = p;
    zloc += p;
  }
  red[t] = zloc;
  __syncthreads();
  for (int off = 128; off > 0; off >>= 1) {
    if (t < off) red[t] += red[t + off];
    __syncthreads();
  }
  float Z = red[0];
  __syncthreads();
  // Z >= 1 structurally; guard keeps a (hypothetical) select bug finite.
  float invZ = (Z > 0.0f) ? (1.0f / Z) : 0.0f;

  // PV: thread t -> dim d = t&127, half of i-range per (t>>7)
  int d = t & 127, half = t >> 7;
  float acc = 0.f;
  for (int i = half * 512; i < half * 512 + 512; ++i) {
    float p = sc[i];
    if (p != 0.0f)
      acc += p * vtmp[(size_t)(b * S_ + i) * KSTRIDE + g * HD_ + d];
  }
  red[t] = acc;
  __syncthreads();
  if (t < 128) {
    float val = (red[t] + red[t + 128]) * invZ;
    qseg[d] = val;  // in place over this block's own Q segment
  }
}

// ---------------------------------------------------------------------------
extern "C" void kernel_launch(void* const* d_in, const int* in_sizes, int n_in,
                              void* d_out, int out_size, void* d_ws,
                              size_t ws_size, hipStream_t stream) {
  // All tensors are float32 per the reference; position_ids is int32.
  const float* hidden = (const float*)d_in[0];
  const float* wq = (const float*)d_in[1];
  const float* bq = (const float*)d_in[2];
  const float* wk = (const float*)d_in[3];
  const float* bk = (const float*)d_in[4];
  const float* wv = (const float*)d_in[5];
  const float* bv = (const float*)d_in[6];
  const float* wo = (const float*)d_in[7];
  const float* bo = (const float*)d_in[8];
  const int* pos = (const int*)d_in[9];
  float* out = (float*)d_out;

  char* ws = (char*)d_ws;
  // ws layout (bytes): qtmp 16MB | ktmp 8MB | vtmp 8MB = 32MB total.
  // qtmp doubles as the attention output buffer (in-place per block).
  float* qtmp = (float*)ws;
  float* ktmp = (float*)(ws + ((size_t)16 << 20));
  float* vtmp = (float*)(ws + ((size_t)24 << 20));

  const int M = B_ * S_;  // 2048 tokens
  dim3 blk(256);
  // projections (fp32)
  gemm_bias<<<dim3(QSTRIDE / 64, M / 64), blk, 0, stream>>>(hidden, wq, bq,
                                                            qtmp, QSTRIDE, H_);
  gemm_bias<<<dim3(KSTRIDE / 64, M / 64), blk, 0, stream>>>(hidden, wk, bk,
                                                            ktmp, KSTRIDE, H_);
  gemm_bias<<<dim3(KSTRIDE / 64, M / 64), blk, 0, stream>>>(hidden, wv, bv,
                                                            vtmp, KSTRIDE, H_);
  // in-place RoPE on q and k
  rope_inplace<<<dim3(S_, NH_ + NKV_, B_), dim3(64), 0, stream>>>(qtmp, ktmp,
                                                                  pos);
  // sparse attention (output written in place into qtmp)
  attn_kernel<<<dim3(S_, NH_, B_), blk, 0, stream>>>(qtmp, ktmp, vtmp);
  // output projection -> fp32 out
  gemm_bias<<<dim3(H_ / 64, M / 64), blk, 0, stream>>>(qtmp, wo, bo, out, H_,
                                                       H_);
}

// Round 4
// 3226.964 us; speedup vs baseline: 1.1505x; 1.1505x over previous
//
#include <hip/hip_runtime.h>
#include <hip/hip_bf16.h>

// Problem constants
constexpr int B_ = 2, S_ = 1024, H_ = 2048;
constexpr int NH_ = 16, NKV_ = 8, HD_ = 128, GROUPS_ = 2;
constexpr int TOPK_ = 409;  // int(0.4 * 1024)
constexpr int QSTRIDE = NH_ * HD_;   // 2048
constexpr int KSTRIDE = NKV_ * HD_;  // 1024

__device__ inline unsigned fkey(float x) {
  unsigned u = __float_as_uint(x);
  return (u & 0x80000000u) ? ~u : (u | 0x80000000u);
}

// ---------------------------------------------------------------------------
// Tiled GEMM: C[m,n] = sum_k A[m,k] * W[n,k] + bias[n]   (all fp32)
// 128x128 tile, 8x8 per thread, BK=16, 256 threads.
// M,K multiples of 128/16; N multiple of 128.
// ---------------------------------------------------------------------------
__global__ __launch_bounds__(256) void gemm_bias(
    const float* __restrict__ A, const float* __restrict__ W,
    const float* __restrict__ bias, float* __restrict__ C, int N, int K) {
  __shared__ float As[16][132];
  __shared__ float Bs[16][132];
  const int tid = threadIdx.x;
  const int m0 = blockIdx.y * 128, n0 = blockIdx.x * 128;
  const int row0 = (tid >> 4) * 8;  // 0..120
  const int col0 = (tid & 15) * 8;  // 0..120
  // staging coords: 2 rows per matrix per thread
  const int srow = tid >> 2;          // 0..63
  const int skk = (tid & 3) * 4;      // 0,4,8,12
  float acc[8][8] = {};
  for (int k0 = 0; k0 < K; k0 += 16) {
#pragma unroll
    for (int p = 0; p < 2; ++p) {
      int m = srow + 64 * p;
      float4 av = *(const float4*)&A[(size_t)(m0 + m) * K + k0 + skk];
      float4 bv = *(const float4*)&W[(size_t)(n0 + m) * K + k0 + skk];
      As[skk + 0][m] = av.x; As[skk + 1][m] = av.y;
      As[skk + 2][m] = av.z; As[skk + 3][m] = av.w;
      Bs[skk + 0][m] = bv.x; Bs[skk + 1][m] = bv.y;
      Bs[skk + 2][m] = bv.z; Bs[skk + 3][m] = bv.w;
    }
    __syncthreads();
#pragma unroll
    for (int kk = 0; kk < 16; ++kk) {
      float4 a0 = *(const float4*)&As[kk][row0];
      float4 a1 = *(const float4*)&As[kk][row0 + 4];
      float4 b0 = *(const float4*)&Bs[kk][col0];
      float4 b1 = *(const float4*)&Bs[kk][col0 + 4];
      float ar[8] = {a0.x, a0.y, a0.z, a0.w, a1.x, a1.y, a1.z, a1.w};
      float br[8] = {b0.x, b0.y, b0.z, b0.w, b1.x, b1.y, b1.z, b1.w};
#pragma unroll
      for (int i = 0; i < 8; ++i)
#pragma unroll
        for (int j = 0; j < 8; ++j) acc[i][j] += ar[i] * br[j];
    }
    __syncthreads();
  }
  float4 bb0 = *(const float4*)&bias[n0 + col0];
  float4 bb1 = *(const float4*)&bias[n0 + col0 + 4];
  float bbr[8] = {bb0.x, bb0.y, bb0.z, bb0.w, bb1.x, bb1.y, bb1.z, bb1.w};
#pragma unroll
  for (int i = 0; i < 8; ++i) {
    int m = m0 + row0 + i;
    float4 o0 = {acc[i][0] + bbr[0], acc[i][1] + bbr[1], acc[i][2] + bbr[2],
                 acc[i][3] + bbr[3]};
    float4 o1 = {acc[i][4] + bbr[4], acc[i][5] + bbr[5], acc[i][6] + bbr[6],
                 acc[i][7] + bbr[7]};
    *(float4*)&C[(size_t)m * N + n0 + col0] = o0;
    *(float4*)&C[(size_t)m * N + n0 + col0 + 4] = o1;
  }
}

// ---------------------------------------------------------------------------
// In-place RoPE on qtmp [token, NH*HD] and ktmp [token, NKV*HD].
// grid: (S, NH+NKV, B), block: 64 (thread d handles the pair d, d+64)
// ---------------------------------------------------------------------------
__global__ __launch_bounds__(64) void rope_inplace(
    float* __restrict__ qtmp, float* __restrict__ ktmp,
    const int* __restrict__ pos_ids) {
  const int s = blockIdx.x;
  const int hh = blockIdx.y;
  const int b = blockIdx.z;
  const int d = threadIdx.x;  // 0..63
  const int pos = pos_ids[b * S_ + s];
  float* ptr;
  if (hh < NH_) {
    ptr = qtmp + (size_t)(b * S_ + s) * QSTRIDE + hh * HD_;
  } else {
    ptr = ktmp + (size_t)(b * S_ + s) * KSTRIDE + (hh - NH_) * HD_;
  }
  float x = ptr[d], y = ptr[d + 64];
  float f = (float)(1.0 / pow(1.0e6, (double)d / 64.0));
  float ang = (float)pos * f;
  float c = cosf(ang), sn = sinf(ang);
  ptr[d] = x * c - y * sn;
  ptr[d + 64] = y * c + x * sn;
}

// ---------------------------------------------------------------------------
// Sparse attention, one block (256 thr) per (b, h, query) row.
// QK: q in registers (32-dim chunk/thread), 4-lane shfl reduce.
// Exact 409th-largest via 4-pass radix select w/ wave-level suffix scan.
// PV over ballot-compacted kept-index list, float4 V loads.
// Output written in place over the block's own Q segment.
// ---------------------------------------------------------------------------
__global__ __launch_bounds__(256) void attn_kernel(
    float* __restrict__ qtmp, const float* __restrict__ ktmp,
    const float* __restrict__ vtmp) {
  const int qs = blockIdx.x;
  const int h = blockIdx.y;
  const int b = blockIdx.z;
  const int g = h / GROUPS_;
  const int t = threadIdx.x;
  const int lane = t & 63;
  const int wid = t >> 6;
  const int lane_c = t & 3;        // dim chunk within 4-lane group
  const int row_grp = t >> 2;      // 0..63

  __shared__ float sc[S_];
  __shared__ unsigned keys[S_];
  __shared__ int idxlist[S_];
  __shared__ unsigned hist[256];
  __shared__ float redmx[4];
  __shared__ float redz[4];
  __shared__ unsigned redu[4];
  __shared__ unsigned sh_prefix;
  __shared__ int sh_kk;
  __shared__ int sh_cnt;
  __shared__ float4 pvred[8][32];
  const float scale = 0.08838834764831845f;  // 1/sqrt(128)

  float* qseg = qtmp + (size_t)(b * S_ + qs) * QSTRIDE + h * HD_;

  // ---- q chunk into registers (8 float4 = 32 dims) ----
  const float4* q4 = (const float4*)(qseg + lane_c * 32);
  float4 qv[8];
#pragma unroll
  for (int j = 0; j < 8; ++j) qv[j] = q4[j];

  if (t == 0) sh_cnt = 0;

  // ---- QK^T: 16 rows per 4-lane group ----
  const float* kbase = ktmp + (size_t)(b * S_) * KSTRIDE + g * HD_ + lane_c * 32;
  float mloc = -1e30f;
#pragma unroll
  for (int it = 0; it < 16; ++it) {
    int r = row_grp + it * 64;
    const float4* k4 = (const float4*)(kbase + (size_t)r * KSTRIDE);
    float acc = 0.f;
#pragma unroll
    for (int j = 0; j < 8; ++j) {
      float4 kv = k4[j];
      acc += qv[j].x * kv.x + qv[j].y * kv.y + qv[j].z * kv.z + qv[j].w * kv.w;
    }
    acc += __shfl_xor(acc, 1);
    acc += __shfl_xor(acc, 2);
    float sval = acc * scale;
    if (lane_c == 0) {
      sc[r] = sval;
      keys[r] = fkey(sval);
    }
    mloc = fmaxf(mloc, sval);
  }
  // block max: wave reduce (waves own disjoint row sets) then cross-wave
#pragma unroll
  for (int off = 4; off < 64; off <<= 1) mloc = fmaxf(mloc, __shfl_xor(mloc, off));
  if (lane == 0) redmx[wid] = mloc;
  __syncthreads();  // sc/keys/redmx/sh_cnt visible
  float mx = fmaxf(fmaxf(redmx[0], redmx[1]), fmaxf(redmx[2], redmx[3]));

  // ---- radix select: exact key of the TOPK_-th largest ----
  int kk = TOPK_;
  unsigned prefix = 0;
  for (int pass = 0; pass < 4; ++pass) {
    const int shift = 24 - 8 * pass;
    const unsigned pmask = pass ? (0xFFFFFFFFu << (shift + 8)) : 0u;
    hist[t] = 0;
    __syncthreads();
#pragma unroll
    for (int r2 = 0; r2 < 4; ++r2) {
      unsigned u = keys[t + r2 * 256];
      if ((u & pmask) == (prefix & pmask))
        atomicAdd(&hist[(u >> shift) & 0xFF], 1u);
    }
    __syncthreads();
    unsigned cnt = hist[t];
    // suffix sum over this wave's 64 bins (bin = t)
    unsigned suf = cnt;
#pragma unroll
    for (int off = 1; off < 64; off <<= 1) {
      unsigned vv = __shfl_down(suf, off);
      if (lane + off < 64) suf += vv;
    }
    if (lane == 0) redu[wid] = suf;  // wave-total
    __syncthreads();
    unsigned above_waves = 0;
#pragma unroll
    for (int w = 0; w < 4; ++w)
      if (w > wid) above_waves += redu[w];
    unsigned suffix = suf + above_waves;   // count of candidates with digit >= t
    unsigned above = suffix - cnt;         // digit > t
    if (suffix >= (unsigned)kk && above < (unsigned)kk) {
      sh_prefix = prefix | ((unsigned)t << shift);
      sh_kk = kk - (int)above;
    }
    __syncthreads();
    prefix = sh_prefix;
    kk = sh_kk;
  }

  // ---- masked softmax numerators + ballot-compacted kept list ----
  float zloc = 0.f;
#pragma unroll
  for (int r2 = 0; r2 < 4; ++r2) {
    int i = t + r2 * 256;
    bool keep = (keys[i] >= prefix);
    float p = keep ? __expf(sc[i] - mx) : 0.0f;
    sc[i] = p;
    zloc += p;
    unsigned long long m = __ballot(keep);
    int base = 0;
    if (lane == 0 && m) base = atomicAdd(&sh_cnt, __popcll(m));
    base = __shfl(base, 0);
    if (keep) {
      int mypos = base + __popcll(m & ((1ull << lane) - 1ull));
      idxlist[mypos] = i;
    }
  }
#pragma unroll
  for (int off = 1; off < 64; off <<= 1) zloc += __shfl_xor(zloc, off);
  if (lane == 0) redz[wid] = zloc;
  __syncthreads();  // idxlist/sh_cnt/redz visible
  float Z = redz[0] + redz[1] + redz[2] + redz[3];
  float invZ = (Z > 0.f) ? (1.0f / Z) : 0.f;  // Z >= 1 structurally
  int ncnt = sh_cnt;

  // ---- PV over kept list: 8 groups x 32 lanes (float4 per lane) ----
  const int dq = t & 31;   // float4 index: dims 4dq..4dq+3
  const int gg = t >> 5;   // 0..7
  const float* vbase = vtmp + (size_t)(b * S_) * KSTRIDE + g * HD_;
  float4 acc4 = {0.f, 0.f, 0.f, 0.f};
  for (int j = gg; j < ncnt; j += 8) {
    int i = idxlist[j];
    float p = sc[i];
    float4 vv = *(const float4*)(vbase + (size_t)i * KSTRIDE + dq * 4);
    acc4.x += p * vv.x;
    acc4.y += p * vv.y;
    acc4.z += p * vv.z;
    acc4.w += p * vv.w;
  }
  pvred[gg][dq] = acc4;
  __syncthreads();
  if (t < 32) {
    float4 s = pvred[0][t];
#pragma unroll
    for (int w = 1; w < 8; ++w) {
      float4 x = pvred[w][t];
      s.x += x.x; s.y += x.y; s.z += x.z; s.w += x.w;
    }
    s.x *= invZ; s.y *= invZ; s.z *= invZ; s.w *= invZ;
    ((float4*)qseg)[t] = s;
  }
}

// ---------------------------------------------------------------------------
extern "C" void kernel_launch(void* const* d_in, const int* in_sizes, int n_in,
                              void* d_out, int out_size, void* d_ws,
                              size_t ws_size, hipStream_t stream) {
  // All tensors are float32 per the reference; position_ids is int32.
  const float* hidden = (const float*)d_in[0];
  const float* wq = (const float*)d_in[1];
  const float* bq = (const float*)d_in[2];
  const float* wk = (const float*)d_in[3];
  const float* bk = (const float*)d_in[4];
  const float* wv = (const float*)d_in[5];
  const float* bv = (const float*)d_in[6];
  const float* wo = (const float*)d_in[7];
  const float* bo = (const float*)d_in[8];
  const int* pos = (const int*)d_in[9];
  float* out = (float*)d_out;

  char* ws = (char*)d_ws;
  // ws layout (bytes): qtmp 16MB | ktmp 8MB | vtmp 8MB = 32MB total.
  // qtmp doubles as the attention output buffer (in-place per block).
  float* qtmp = (float*)ws;
  float* ktmp = (float*)(ws + ((size_t)16 << 20));
  float* vtmp = (float*)(ws + ((size_t)24 << 20));

  const int M = B_ * S_;  // 2048 tokens
  dim3 blk(256);
  // projections (fp32, 128x128 tiles)
  gemm_bias<<<dim3(QSTRIDE / 128, M / 128), blk, 0, stream>>>(hidden, wq, bq,
                                                              qtmp, QSTRIDE, H_);
  gemm_bias<<<dim3(KSTRIDE / 128, M / 128), blk, 0, stream>>>(hidden, wk, bk,
                                                              ktmp, KSTRIDE, H_);
  gemm_bias<<<dim3(KSTRIDE / 128, M / 128), blk, 0, stream>>>(hidden, wv, bv,
                                                              vtmp, KSTRIDE, H_);
  // in-place RoPE on q and k
  rope_inplace<<<dim3(S_, NH_ + NKV_, B_), dim3(64), 0, stream>>>(qtmp, ktmp,
                                                                  pos);
  // sparse attention (output written in place into qtmp)
  attn_kernel<<<dim3(S_, NH_, B_), blk, 0, stream>>>(qtmp, ktmp, vtmp);
  // output projection -> fp32 out
  gemm_bias<<<dim3(H_ / 128, M / 128), blk, 0, stream>>>(qtmp, wo, bo, out, H_,
                                                         H_);
}

// Round 5
// 1806.760 us; speedup vs baseline: 2.0549x; 1.7860x over previous
//
#include <hip/hip_runtime.h>
#include <hip/hip_bf16.h>

// Problem constants
constexpr int B_ = 2, S_ = 1024, H_ = 2048;
constexpr int NH_ = 16, NKV_ = 8, HD_ = 128, GROUPS_ = 2;
constexpr int TOPK_ = 409;  // int(0.4 * 1024)
constexpr int QSTRIDE = NH_ * HD_;   // 2048
constexpr int KSTRIDE = NKV_ * HD_;  // 1024
constexpr int QB_ = 8;               // queries per attention block

__device__ inline unsigned fkey(float x) {
  unsigned u = __float_as_uint(x);
  return (u & 0x80000000u) ? ~u : (u | 0x80000000u);
}

// ---------------------------------------------------------------------------
// Tiled GEMM: C[m,n] = sum_k A[m,k] * W[n,k] + bias[n]   (all fp32)
// 128x128 tile, 8x8 per thread, BK=16, 256 threads.  (unchanged from R4)
// ---------------------------------------------------------------------------
__global__ __launch_bounds__(256) void gemm_bias(
    const float* __restrict__ A, const float* __restrict__ W,
    const float* __restrict__ bias, float* __restrict__ C, int N, int K) {
  __shared__ float As[16][132];
  __shared__ float Bs[16][132];
  const int tid = threadIdx.x;
  const int m0 = blockIdx.y * 128, n0 = blockIdx.x * 128;
  const int row0 = (tid >> 4) * 8;
  const int col0 = (tid & 15) * 8;
  const int srow = tid >> 2;
  const int skk = (tid & 3) * 4;
  float acc[8][8] = {};
  for (int k0 = 0; k0 < K; k0 += 16) {
#pragma unroll
    for (int p = 0; p < 2; ++p) {
      int m = srow + 64 * p;
      float4 av = *(const float4*)&A[(size_t)(m0 + m) * K + k0 + skk];
      float4 bv = *(const float4*)&W[(size_t)(n0 + m) * K + k0 + skk];
      As[skk + 0][m] = av.x; As[skk + 1][m] = av.y;
      As[skk + 2][m] = av.z; As[skk + 3][m] = av.w;
      Bs[skk + 0][m] = bv.x; Bs[skk + 1][m] = bv.y;
      Bs[skk + 2][m] = bv.z; Bs[skk + 3][m] = bv.w;
    }
    __syncthreads();
#pragma unroll
    for (int kk = 0; kk < 16; ++kk) {
      float4 a0 = *(const float4*)&As[kk][row0];
      float4 a1 = *(const float4*)&As[kk][row0 + 4];
      float4 b0 = *(const float4*)&Bs[kk][col0];
      float4 b1 = *(const float4*)&Bs[kk][col0 + 4];
      float ar[8] = {a0.x, a0.y, a0.z, a0.w, a1.x, a1.y, a1.z, a1.w};
      float br[8] = {b0.x, b0.y, b0.z, b0.w, b1.x, b1.y, b1.z, b1.w};
#pragma unroll
      for (int i = 0; i < 8; ++i)
#pragma unroll
        for (int j = 0; j < 8; ++j) acc[i][j] += ar[i] * br[j];
    }
    __syncthreads();
  }
  float4 bb0 = *(const float4*)&bias[n0 + col0];
  float4 bb1 = *(const float4*)&bias[n0 + col0 + 4];
  float bbr[8] = {bb0.x, bb0.y, bb0.z, bb0.w, bb1.x, bb1.y, bb1.z, bb1.w};
#pragma unroll
  for (int i = 0; i < 8; ++i) {
    int m = m0 + row0 + i;
    float4 o0 = {acc[i][0] + bbr[0], acc[i][1] + bbr[1], acc[i][2] + bbr[2],
                 acc[i][3] + bbr[3]};
    float4 o1 = {acc[i][4] + bbr[4], acc[i][5] + bbr[5], acc[i][6] + bbr[6],
                 acc[i][7] + bbr[7]};
    *(float4*)&C[(size_t)m * N + n0 + col0] = o0;
    *(float4*)&C[(size_t)m * N + n0 + col0 + 4] = o1;
  }
}

// ---------------------------------------------------------------------------
// In-place RoPE (unchanged from R4)
// ---------------------------------------------------------------------------
__global__ __launch_bounds__(64) void rope_inplace(
    float* __restrict__ qtmp, float* __restrict__ ktmp,
    const int* __restrict__ pos_ids) {
  const int s = blockIdx.x;
  const int hh = blockIdx.y;
  const int b = blockIdx.z;
  const int d = threadIdx.x;
  const int pos = pos_ids[b * S_ + s];
  float* ptr;
  if (hh < NH_) {
    ptr = qtmp + (size_t)(b * S_ + s) * QSTRIDE + hh * HD_;
  } else {
    ptr = ktmp + (size_t)(b * S_ + s) * KSTRIDE + (hh - NH_) * HD_;
  }
  float x = ptr[d], y = ptr[d + 64];
  float f = (float)(1.0 / pow(1.0e6, (double)d / 64.0));
  float ang = (float)pos * f;
  float c = cosf(ang), sn = sinf(ang);
  ptr[d] = x * c - y * sn;
  ptr[d + 64] = y * c + x * sn;
}

// ---------------------------------------------------------------------------
// Sparse attention v3: one block per (b, h, 8 queries). K/V staged in LDS
// tiles (reused by all 8 queries). Dense PV (masked probs, zeros multiply).
// Exact top-k threshold per query via per-wave 4-pass radix select.
// ---------------------------------------------------------------------------
__global__ __launch_bounds__(256, 2) void attn_kernel(
    float* __restrict__ qtmp, const float* __restrict__ ktmp,
    const float* __restrict__ vtmp) {
  const int q0 = blockIdx.x * QB_;
  const int h = blockIdx.y;
  const int b = blockIdx.z;
  const int g = h / GROUPS_;
  const int t = threadIdx.x;
  const int lane = t & 63;
  const int wid = t >> 6;

  __shared__ float sc[QB_][S_];        // 32 KB  scores -> probs
  __shared__ float k_sh[32][132];      // 16.9 KB K/V tile
  __shared__ float q_sh[QB_][HD_];     // 4 KB
  __shared__ unsigned hist[4][256];    // 4 KB   per-wave radix histograms
  __shared__ float redmx[4][4];        // per-wave partial max, 4 queries
  __shared__ float Zsh[QB_];
  __shared__ unsigned prefix_sh[QB_];
  __shared__ unsigned selbin_sh[4];
  __shared__ int selkk_sh[4];
  __shared__ float4 pvred[4][QB_][32]; // 16 KB  PV cross-wave partials
  const float scale = 0.08838834764831845f;  // 1/sqrt(128)

  // ---- stage Q block into LDS (8 x 128 floats), then into registers ----
  {
    int qi = t >> 5, f4 = t & 31;
    float4 vv = *(const float4*)&qtmp[(size_t)(b * S_ + q0 + qi) * QSTRIDE +
                                      h * HD_ + 4 * f4];
    *(float4*)&q_sh[qi][4 * f4] = vv;
  }
  __syncthreads();

  // QK thread mapping: qgrp (4 queries) x key-row slot x dim chunk
  const int qgrp = t >> 7;         // 0..1 -> queries qgrp*4..+3
  const int kr = (t >> 2) & 31;    // 0..31 key-row slot
  const int c = t & 3;             // dim chunk (32 dims)
  float4 qv[4][8];
#pragma unroll
  for (int qq = 0; qq < 4; ++qq)
#pragma unroll
    for (int j = 0; j < 8; ++j)
      qv[qq][j] = *(const float4*)&q_sh[qgrp * 4 + qq][c * 32 + 4 * j];

  // ---- QK^T over 32-row K tiles ----
  const float* kgbase = ktmp + (size_t)(b * S_) * KSTRIDE + g * HD_;
  float mloc[4] = {-1e30f, -1e30f, -1e30f, -1e30f};
  const int srr = t >> 3;       // staging: row 0..31
  const int spos = t & 7;       // staging: float4 slot 0..7
  for (int tile = 0; tile < 32; ++tile) {
    __syncthreads();
    {
      const float* src = kgbase + (size_t)(tile * 32 + srr) * KSTRIDE;
#pragma unroll
      for (int j = 0; j < 4; ++j) {
        float4 vv = *(const float4*)&src[(spos + 8 * j) * 4];
        *(float4*)&k_sh[srr][(spos + 8 * j) * 4] = vv;
      }
    }
    __syncthreads();
    float4 kv[8];
#pragma unroll
    for (int j = 0; j < 8; ++j)
      kv[j] = *(const float4*)&k_sh[kr][c * 32 + 4 * j];
#pragma unroll
    for (int qq = 0; qq < 4; ++qq) {
      float acc = 0.f;
#pragma unroll
      for (int j = 0; j < 8; ++j) {
        acc += qv[qq][j].x * kv[j].x + qv[qq][j].y * kv[j].y +
               qv[qq][j].z * kv[j].z + qv[qq][j].w * kv[j].w;
      }
      acc += __shfl_xor(acc, 1);
      acc += __shfl_xor(acc, 2);
      float sval = acc * scale;  // all 4 lanes of the c-group hold the sum
      if (c == 0) sc[qgrp * 4 + qq][tile * 32 + kr] = sval;
      mloc[qq] = fmaxf(mloc[qq], sval);
    }
  }
  // per-wave max for its 4 queries (wave covers kr subset of its qgrp)
#pragma unroll
  for (int qq = 0; qq < 4; ++qq) {
    float m = mloc[qq];
#pragma unroll
    for (int off = 1; off < 64; off <<= 1) m = fmaxf(m, __shfl_xor(m, off));
    if (lane == 0) redmx[wid][qq] = m;
  }
  __syncthreads();

  // ---- per-wave radix select: wave wid -> queries 2*wid, 2*wid+1 ----
  for (int sq = 0; sq < 2; ++sq) {
    const int qi = wid * 2 + sq;
    int kk = TOPK_;
    unsigned prefix = 0;
    for (int pass = 0; pass < 4; ++pass) {
      const int shift = 24 - 8 * pass;
      const unsigned pmask = pass ? (0xFFFFFFFFu << (shift + 8)) : 0u;
#pragma unroll
      for (int j = 0; j < 4; ++j) hist[wid][4 * lane + j] = 0;
      __syncthreads();
#pragma unroll 4
      for (int j = 0; j < 16; ++j) {
        unsigned u = fkey(sc[qi][lane + 64 * j]);
        if ((u & pmask) == (prefix & pmask))
          atomicAdd(&hist[wid][(u >> shift) & 255], 1u);
      }
      __syncthreads();
      int c0 = (int)hist[wid][4 * lane + 0];
      int c1 = (int)hist[wid][4 * lane + 1];
      int c2 = (int)hist[wid][4 * lane + 2];
      int c3 = (int)hist[wid][4 * lane + 3];
      int s3 = c3, s2 = c2 + s3, s1 = c1 + s2, s0 = c0 + s1;
      int tot = s0;
      int suf = tot;  // inclusive suffix over lane totals (lanes >= lane)
#pragma unroll
      for (int off = 1; off < 64; off <<= 1) {
        int vv = __shfl_down(suf, off);
        if (lane + off < 64) suf += vv;
      }
      int above_lanes = suf - tot;  // lanes > lane
      int i0 = s0 + above_lanes, i1 = s1 + above_lanes;
      int i2 = s2 + above_lanes, i3 = s3 + above_lanes;
      // exactly one bin in the wave satisfies: incl >= kk && incl - cnt < kk
      if (i3 >= kk && i3 - c3 < kk) {
        selbin_sh[wid] = (unsigned)(4 * lane + 3); selkk_sh[wid] = kk - (i3 - c3);
      }
      if (i2 >= kk && i2 - c2 < kk) {
        selbin_sh[wid] = (unsigned)(4 * lane + 2); selkk_sh[wid] = kk - (i2 - c2);
      }
      if (i1 >= kk && i1 - c1 < kk) {
        selbin_sh[wid] = (unsigned)(4 * lane + 1); selkk_sh[wid] = kk - (i1 - c1);
      }
      if (i0 >= kk && i0 - c0 < kk) {
        selbin_sh[wid] = (unsigned)(4 * lane + 0); selkk_sh[wid] = kk - (i0 - c0);
      }
      __syncthreads();
      prefix |= selbin_sh[wid] << shift;
      kk = selkk_sh[wid];
    }
    if (lane == 0) prefix_sh[qi] = prefix;
  }
  __syncthreads();

  // ---- masked softmax numerators (query-major mapping) ----
  {
    const int qi = t >> 5, li = t & 31;
    const float mx =
        fmaxf(redmx[(qi >> 2) * 2][qi & 3], redmx[(qi >> 2) * 2 + 1][qi & 3]);
    const unsigned pref = prefix_sh[qi];
    float zloc = 0.f;
#pragma unroll 8
    for (int j = 0; j < 32; ++j) {
      int i = li + 32 * j;
      float s = sc[qi][i];
      float p = (fkey(s) >= pref) ? __expf(s - mx) : 0.0f;
      sc[qi][i] = p;
      zloc += p;
    }
#pragma unroll
    for (int off = 1; off < 32; off <<= 1) zloc += __shfl_xor(zloc, off);
    if (li == 0) Zsh[qi] = zloc;
  }
  __syncthreads();

  // ---- dense PV over 32-row V tiles ----
  const int dq = t & 31;           // float4 of dims
  const int qquad = (t >> 5) & 1;  // queries qquad*4..+3
  const int kh = t >> 6;           // wave -> rows kh*8..+7 of each tile
  const float* vgbase = vtmp + (size_t)(b * S_) * KSTRIDE + g * HD_;
  float4 acc4[4] = {{0.f, 0.f, 0.f, 0.f},
                    {0.f, 0.f, 0.f, 0.f},
                    {0.f, 0.f, 0.f, 0.f},
                    {0.f, 0.f, 0.f, 0.f}};
  for (int tile = 0; tile < 32; ++tile) {
    __syncthreads();
    {
      const float* src = vgbase + (size_t)(tile * 32 + srr) * KSTRIDE;
#pragma unroll
      for (int j = 0; j < 4; ++j) {
        float4 vv = *(const float4*)&src[(spos + 8 * j) * 4];
        *(float4*)&k_sh[srr][(spos + 8 * j) * 4] = vv;
      }
    }
    __syncthreads();
#pragma unroll
    for (int r = 0; r < 8; ++r) {
      int rr = kh * 8 + r;
      int i = tile * 32 + rr;
      float4 vv = *(const float4*)&k_sh[rr][4 * dq];
#pragma unroll
      for (int qq = 0; qq < 4; ++qq) {
        float p = sc[qquad * 4 + qq][i];
        acc4[qq].x += p * vv.x;
        acc4[qq].y += p * vv.y;
        acc4[qq].z += p * vv.z;
        acc4[qq].w += p * vv.w;
      }
    }
  }
  __syncthreads();
#pragma unroll
  for (int qq = 0; qq < 4; ++qq) pvred[kh][qquad * 4 + qq][dq] = acc4[qq];
  __syncthreads();

  // ---- epilogue: reduce 4 wave-partials, scale by 1/Z, write out ----
  {
    const int qi = t >> 5, df = t & 31;
    float4 s = pvred[0][qi][df];
#pragma unroll
    for (int w = 1; w < 4; ++w) {
      float4 x = pvred[w][qi][df];
      s.x += x.x; s.y += x.y; s.z += x.z; s.w += x.w;
    }
    float invZ = 1.0f / Zsh[qi];  // Z >= 1 structurally
    s.x *= invZ; s.y *= invZ; s.z *= invZ; s.w *= invZ;
    *(float4*)&qtmp[(size_t)(b * S_ + q0 + qi) * QSTRIDE + h * HD_ + 4 * df] = s;
  }
}

// ---------------------------------------------------------------------------
extern "C" void kernel_launch(void* const* d_in, const int* in_sizes, int n_in,
                              void* d_out, int out_size, void* d_ws,
                              size_t ws_size, hipStream_t stream) {
  // All tensors are float32 per the reference; position_ids is int32.
  const float* hidden = (const float*)d_in[0];
  const float* wq = (const float*)d_in[1];
  const float* bq = (const float*)d_in[2];
  const float* wk = (const float*)d_in[3];
  const float* bk = (const float*)d_in[4];
  const float* wv = (const float*)d_in[5];
  const float* bv = (const float*)d_in[6];
  const float* wo = (const float*)d_in[7];
  const float* bo = (const float*)d_in[8];
  const int* pos = (const int*)d_in[9];
  float* out = (float*)d_out;

  char* ws = (char*)d_ws;
  // ws layout (bytes): qtmp 16MB | ktmp 8MB | vtmp 8MB = 32MB total.
  // qtmp doubles as the attention output buffer (in-place per block).
  float* qtmp = (float*)ws;
  float* ktmp = (float*)(ws + ((size_t)16 << 20));
  float* vtmp = (float*)(ws + ((size_t)24 << 20));

  const int M = B_ * S_;  // 2048 tokens
  dim3 blk(256);
  gemm_bias<<<dim3(QSTRIDE / 128, M / 128), blk, 0, stream>>>(hidden, wq, bq,
                                                              qtmp, QSTRIDE, H_);
  gemm_bias<<<dim3(KSTRIDE / 128, M / 128), blk, 0, stream>>>(hidden, wk, bk,
                                                              ktmp, KSTRIDE, H_);
  gemm_bias<<<dim3(KSTRIDE / 128, M / 128), blk, 0, stream>>>(hidden, wv, bv,
                                                              vtmp, KSTRIDE, H_);
  rope_inplace<<<dim3(S_, NH_ + NKV_, B_), dim3(64), 0, stream>>>(qtmp, ktmp,
                                                                  pos);
  attn_kernel<<<dim3(S_ / QB_, NH_, B_), blk, 0, stream>>>(qtmp, ktmp, vtmp);
  gemm_bias<<<dim3(H_ / 128, M / 128), blk, 0, stream>>>(qtmp, wo, bo, out, H_,
                                                         H_);
}

// Round 6
// 1310.600 us; speedup vs baseline: 2.8329x; 1.3786x over previous
//
#include <hip/hip_runtime.h>
#include <hip/hip_bf16.h>

// Problem constants
constexpr int B_ = 2, S_ = 1024, H_ = 2048;
constexpr int NH_ = 16, NKV_ = 8, HD_ = 128, GROUPS_ = 2;
constexpr int TOPK_ = 409;  // int(0.4 * 1024)
constexpr int QSTRIDE = NH_ * HD_;   // 2048
constexpr int KSTRIDE = NKV_ * HD_;  // 1024
constexpr int QB_ = 8;               // queries per attention block

typedef __attribute__((ext_vector_type(8))) short short8;
typedef __attribute__((ext_vector_type(4))) float f32x4;

__device__ inline unsigned fkey(float x) {
  unsigned u = __float_as_uint(x);
  return (u & 0x80000000u) ? ~u : (u | 0x80000000u);
}

__device__ inline unsigned short bf16_rne(float x) {
  unsigned u = __float_as_uint(x);
  unsigned r = u + 0x7FFFu + ((u >> 16) & 1u);
  return (unsigned short)(r >> 16);
}
__device__ inline float bf16_to_f(unsigned short h) {
  return __uint_as_float((unsigned)h << 16);
}

// ---------------------------------------------------------------------------
// Split-precision bf16 MFMA GEMM: C[m,n] = sum_k A[m,k]*W[n,k] + bias[n]
// A,W fp32 in global; converted to hi/lo bf16 during LDS staging.
// a*b ~= ah*bh + ah*bl + al*bh  (3 MFMAs, fp32-grade accuracy).
// 128x128 tile, BK=32, 256 threads (4 waves, 2x2 of 64x64).
// ---------------------------------------------------------------------------
__global__ __launch_bounds__(256) void gemm_mfma_split(
    const float* __restrict__ A, const float* __restrict__ W,
    const float* __restrict__ bias, float* __restrict__ C, int N, int K) {
  __shared__ unsigned short Ah[128][32];
  __shared__ unsigned short Al[128][32];
  __shared__ unsigned short Wh[128][32];
  __shared__ unsigned short Wl[128][32];
  const int tid = threadIdx.x;
  const int m0 = blockIdx.y * 128, n0 = blockIdx.x * 128;
  const int lane = tid & 63, wid = tid >> 6;
  const int wrow = (wid >> 1) * 64, wcol = (wid & 1) * 64;
  const int fm = lane & 15, quad = lane >> 4;
  const int srow = tid >> 3;            // staging row 0..31 (base)
  const int skq = (tid & 7) * 4;        // staging k offset 0,4,..,28

  f32x4 acc[4][4] = {};

  for (int k0 = 0; k0 < K; k0 += 32) {
    __syncthreads();
#pragma unroll
    for (int r = 0; r < 4; ++r) {
      int row = srow + 32 * r;
      float4 av = *(const float4*)&A[(size_t)(m0 + row) * K + k0 + skq];
      float4 wv = *(const float4*)&W[(size_t)(n0 + row) * K + k0 + skq];
      unsigned short h0 = bf16_rne(av.x), h1 = bf16_rne(av.y),
                     h2 = bf16_rne(av.z), h3 = bf16_rne(av.w);
      Ah[row][skq + 0] = h0; Ah[row][skq + 1] = h1;
      Ah[row][skq + 2] = h2; Ah[row][skq + 3] = h3;
      Al[row][skq + 0] = bf16_rne(av.x - bf16_to_f(h0));
      Al[row][skq + 1] = bf16_rne(av.y - bf16_to_f(h1));
      Al[row][skq + 2] = bf16_rne(av.z - bf16_to_f(h2));
      Al[row][skq + 3] = bf16_rne(av.w - bf16_to_f(h3));
      unsigned short g0 = bf16_rne(wv.x), g1 = bf16_rne(wv.y),
                     g2 = bf16_rne(wv.z), g3 = bf16_rne(wv.w);
      Wh[row][skq + 0] = g0; Wh[row][skq + 1] = g1;
      Wh[row][skq + 2] = g2; Wh[row][skq + 3] = g3;
      Wl[row][skq + 0] = bf16_rne(wv.x - bf16_to_f(g0));
      Wl[row][skq + 1] = bf16_rne(wv.y - bf16_to_f(g1));
      Wl[row][skq + 2] = bf16_rne(wv.z - bf16_to_f(g2));
      Wl[row][skq + 3] = bf16_rne(wv.w - bf16_to_f(g3));
    }
    __syncthreads();
    short8 ah[4], al[4], bh[4], bl[4];
#pragma unroll
    for (int ti = 0; ti < 4; ++ti) {
      ah[ti] = *(const short8*)&Ah[wrow + 16 * ti + fm][quad * 8];
      al[ti] = *(const short8*)&Al[wrow + 16 * ti + fm][quad * 8];
    }
#pragma unroll
    for (int tj = 0; tj < 4; ++tj) {
      bh[tj] = *(const short8*)&Wh[wcol + 16 * tj + fm][quad * 8];
      bl[tj] = *(const short8*)&Wl[wcol + 16 * tj + fm][quad * 8];
    }
#pragma unroll
    for (int ti = 0; ti < 4; ++ti)
#pragma unroll
      for (int tj = 0; tj < 4; ++tj) {
        acc[ti][tj] = __builtin_amdgcn_mfma_f32_16x16x32_bf16(
            ah[ti], bh[tj], acc[ti][tj], 0, 0, 0);
        acc[ti][tj] = __builtin_amdgcn_mfma_f32_16x16x32_bf16(
            ah[ti], bl[tj], acc[ti][tj], 0, 0, 0);
        acc[ti][tj] = __builtin_amdgcn_mfma_f32_16x16x32_bf16(
            al[ti], bh[tj], acc[ti][tj], 0, 0, 0);
      }
  }

  // epilogue: C[m0+wrow+16ti+quad*4+reg][n0+wcol+16tj+fm] = acc + bias
#pragma unroll
  for (int tj = 0; tj < 4; ++tj) {
    float bsv = bias[n0 + wcol + 16 * tj + fm];
#pragma unroll
    for (int ti = 0; ti < 4; ++ti) {
      int mrow = m0 + wrow + 16 * ti + quad * 4;
      int ncol = n0 + wcol + 16 * tj + fm;
#pragma unroll
      for (int reg = 0; reg < 4; ++reg) {
        C[(size_t)(mrow + reg) * N + ncol] = acc[ti][tj][reg] + bsv;
      }
    }
  }
}

// ---------------------------------------------------------------------------
// In-place RoPE (unchanged)
// ---------------------------------------------------------------------------
__global__ __launch_bounds__(64) void rope_inplace(
    float* __restrict__ qtmp, float* __restrict__ ktmp,
    const int* __restrict__ pos_ids) {
  const int s = blockIdx.x;
  const int hh = blockIdx.y;
  const int b = blockIdx.z;
  const int d = threadIdx.x;
  const int pos = pos_ids[b * S_ + s];
  float* ptr;
  if (hh < NH_) {
    ptr = qtmp + (size_t)(b * S_ + s) * QSTRIDE + hh * HD_;
  } else {
    ptr = ktmp + (size_t)(b * S_ + s) * KSTRIDE + (hh - NH_) * HD_;
  }
  float x = ptr[d], y = ptr[d + 64];
  float f = (float)(1.0 / pow(1.0e6, (double)d / 64.0));
  float ang = (float)pos * f;
  float c = cosf(ang), sn = sinf(ang);
  ptr[d] = x * c - y * sn;
  ptr[d + 64] = y * c + x * sn;
}

// ---------------------------------------------------------------------------
// Sparse attention v3 (unchanged from R5): one block per (b, h, 8 queries).
// ---------------------------------------------------------------------------
__global__ __launch_bounds__(256, 2) void attn_kernel(
    float* __restrict__ qtmp, const float* __restrict__ ktmp,
    const float* __restrict__ vtmp) {
  const int q0 = blockIdx.x * QB_;
  const int h = blockIdx.y;
  const int b = blockIdx.z;
  const int g = h / GROUPS_;
  const int t = threadIdx.x;
  const int lane = t & 63;
  const int wid = t >> 6;

  __shared__ float sc[QB_][S_];
  __shared__ float k_sh[32][132];
  __shared__ float q_sh[QB_][HD_];
  __shared__ unsigned hist[4][256];
  __shared__ float redmx[4][4];
  __shared__ float Zsh[QB_];
  __shared__ unsigned prefix_sh[QB_];
  __shared__ unsigned selbin_sh[4];
  __shared__ int selkk_sh[4];
  __shared__ float4 pvred[4][QB_][32];
  const float scale = 0.08838834764831845f;  // 1/sqrt(128)

  {
    int qi = t >> 5, f4 = t & 31;
    float4 vv = *(const float4*)&qtmp[(size_t)(b * S_ + q0 + qi) * QSTRIDE +
                                      h * HD_ + 4 * f4];
    *(float4*)&q_sh[qi][4 * f4] = vv;
  }
  __syncthreads();

  const int qgrp = t >> 7;
  const int kr = (t >> 2) & 31;
  const int c = t & 3;
  float4 qv[4][8];
#pragma unroll
  for (int qq = 0; qq < 4; ++qq)
#pragma unroll
    for (int j = 0; j < 8; ++j)
      qv[qq][j] = *(const float4*)&q_sh[qgrp * 4 + qq][c * 32 + 4 * j];

  const float* kgbase = ktmp + (size_t)(b * S_) * KSTRIDE + g * HD_;
  float mloc[4] = {-1e30f, -1e30f, -1e30f, -1e30f};
  const int srr = t >> 3;
  const int spos = t & 7;
  for (int tile = 0; tile < 32; ++tile) {
    __syncthreads();
    {
      const float* src = kgbase + (size_t)(tile * 32 + srr) * KSTRIDE;
#pragma unroll
      for (int j = 0; j < 4; ++j) {
        float4 vv = *(const float4*)&src[(spos + 8 * j) * 4];
        *(float4*)&k_sh[srr][(spos + 8 * j) * 4] = vv;
      }
    }
    __syncthreads();
    float4 kv[8];
#pragma unroll
    for (int j = 0; j < 8; ++j)
      kv[j] = *(const float4*)&k_sh[kr][c * 32 + 4 * j];
#pragma unroll
    for (int qq = 0; qq < 4; ++qq) {
      float acc = 0.f;
#pragma unroll
      for (int j = 0; j < 8; ++j) {
        acc += qv[qq][j].x * kv[j].x + qv[qq][j].y * kv[j].y +
               qv[qq][j].z * kv[j].z + qv[qq][j].w * kv[j].w;
      }
      acc += __shfl_xor(acc, 1);
      acc += __shfl_xor(acc, 2);
      float sval = acc * scale;
      if (c == 0) sc[qgrp * 4 + qq][tile * 32 + kr] = sval;
      mloc[qq] = fmaxf(mloc[qq], sval);
    }
  }
#pragma unroll
  for (int qq = 0; qq < 4; ++qq) {
    float m = mloc[qq];
#pragma unroll
    for (int off = 1; off < 64; off <<= 1) m = fmaxf(m, __shfl_xor(m, off));
    if (lane == 0) redmx[wid][qq] = m;
  }
  __syncthreads();

  for (int sq = 0; sq < 2; ++sq) {
    const int qi = wid * 2 + sq;
    int kk = TOPK_;
    unsigned prefix = 0;
    for (int pass = 0; pass < 4; ++pass) {
      const int shift = 24 - 8 * pass;
      const unsigned pmask = pass ? (0xFFFFFFFFu << (shift + 8)) : 0u;
#pragma unroll
      for (int j = 0; j < 4; ++j) hist[wid][4 * lane + j] = 0;
      __syncthreads();
#pragma unroll 4
      for (int j = 0; j < 16; ++j) {
        unsigned u = fkey(sc[qi][lane + 64 * j]);
        if ((u & pmask) == (prefix & pmask))
          atomicAdd(&hist[wid][(u >> shift) & 255], 1u);
      }
      __syncthreads();
      int c0 = (int)hist[wid][4 * lane + 0];
      int c1 = (int)hist[wid][4 * lane + 1];
      int c2 = (int)hist[wid][4 * lane + 2];
      int c3 = (int)hist[wid][4 * lane + 3];
      int s3 = c3, s2 = c2 + s3, s1 = c1 + s2, s0 = c0 + s1;
      int tot = s0;
      int suf = tot;
#pragma unroll
      for (int off = 1; off < 64; off <<= 1) {
        int vv = __shfl_down(suf, off);
        if (lane + off < 64) suf += vv;
      }
      int above_lanes = suf - tot;
      int i0 = s0 + above_lanes, i1 = s1 + above_lanes;
      int i2 = s2 + above_lanes, i3 = s3 + above_lanes;
      if (i3 >= kk && i3 - c3 < kk) {
        selbin_sh[wid] = (unsigned)(4 * lane + 3); selkk_sh[wid] = kk - (i3 - c3);
      }
      if (i2 >= kk && i2 - c2 < kk) {
        selbin_sh[wid] = (unsigned)(4 * lane + 2); selkk_sh[wid] = kk - (i2 - c2);
      }
      if (i1 >= kk && i1 - c1 < kk) {
        selbin_sh[wid] = (unsigned)(4 * lane + 1); selkk_sh[wid] = kk - (i1 - c1);
      }
      if (i0 >= kk && i0 - c0 < kk) {
        selbin_sh[wid] = (unsigned)(4 * lane + 0); selkk_sh[wid] = kk - (i0 - c0);
      }
      __syncthreads();
      prefix |= selbin_sh[wid] << shift;
      kk = selkk_sh[wid];
    }
    if (lane == 0) prefix_sh[qi] = prefix;
  }
  __syncthreads();

  {
    const int qi = t >> 5, li = t & 31;
    const float mx =
        fmaxf(redmx[(qi >> 2) * 2][qi & 3], redmx[(qi >> 2) * 2 + 1][qi & 3]);
    const unsigned pref = prefix_sh[qi];
    float zloc = 0.f;
#pragma unroll 8
    for (int j = 0; j < 32; ++j) {
      int i = li + 32 * j;
      float s = sc[qi][i];
      float p = (fkey(s) >= pref) ? __expf(s - mx) : 0.0f;
      sc[qi][i] = p;
      zloc += p;
    }
#pragma unroll
    for (int off = 1; off < 32; off <<= 1) zloc += __shfl_xor(zloc, off);
    if (li == 0) Zsh[qi] = zloc;
  }
  __syncthreads();

  const int dq = t & 31;
  const int qquad = (t >> 5) & 1;
  const int kh = t >> 6;
  const float* vgbase = vtmp + (size_t)(b * S_) * KSTRIDE + g * HD_;
  float4 acc4[4] = {{0.f, 0.f, 0.f, 0.f},
                    {0.f, 0.f, 0.f, 0.f},
                    {0.f, 0.f, 0.f, 0.f},
                    {0.f, 0.f, 0.f, 0.f}};
  for (int tile = 0; tile < 32; ++tile) {
    __syncthreads();
    {
      const float* src = vgbase + (size_t)(tile * 32 + srr) * KSTRIDE;
#pragma unroll
      for (int j = 0; j < 4; ++j) {
        float4 vv = *(const float4*)&src[(spos + 8 * j) * 4];
        *(float4*)&k_sh[srr][(spos + 8 * j) * 4] = vv;
      }
    }
    __syncthreads();
#pragma unroll
    for (int r = 0; r < 8; ++r) {
      int rr = kh * 8 + r;
      int i = tile * 32 + rr;
      float4 vv = *(const float4*)&k_sh[rr][4 * dq];
#pragma unroll
      for (int qq = 0; qq < 4; ++qq) {
        float p = sc[qquad * 4 + qq][i];
        acc4[qq].x += p * vv.x;
        acc4[qq].y += p * vv.y;
        acc4[qq].z += p * vv.z;
        acc4[qq].w += p * vv.w;
      }
    }
  }
  __syncthreads();
#pragma unroll
  for (int qq = 0; qq < 4; ++qq) pvred[kh][qquad * 4 + qq][dq] = acc4[qq];
  __syncthreads();

  {
    const int qi = t >> 5, df = t & 31;
    float4 s = pvred[0][qi][df];
#pragma unroll
    for (int w = 1; w < 4; ++w) {
      float4 x = pvred[w][qi][df];
      s.x += x.x; s.y += x.y; s.z += x.z; s.w += x.w;
    }
    float invZ = 1.0f / Zsh[qi];
    s.x *= invZ; s.y *= invZ; s.z *= invZ; s.w *= invZ;
    *(float4*)&qtmp[(size_t)(b * S_ + q0 + qi) * QSTRIDE + h * HD_ + 4 * df] = s;
  }
}

// ---------------------------------------------------------------------------
extern "C" void kernel_launch(void* const* d_in, const int* in_sizes, int n_in,
                              void* d_out, int out_size, void* d_ws,
                              size_t ws_size, hipStream_t stream) {
  // All tensors are float32 per the reference; position_ids is int32.
  const float* hidden = (const float*)d_in[0];
  const float* wq = (const float*)d_in[1];
  const float* bq = (const float*)d_in[2];
  const float* wk = (const float*)d_in[3];
  const float* bk = (const float*)d_in[4];
  const float* wv = (const float*)d_in[5];
  const float* bv = (const float*)d_in[6];
  const float* wo = (const float*)d_in[7];
  const float* bo = (const float*)d_in[8];
  const int* pos = (const int*)d_in[9];
  float* out = (float*)d_out;

  char* ws = (char*)d_ws;
  // ws layout (bytes): qtmp 16MB | ktmp 8MB | vtmp 8MB = 32MB total.
  float* qtmp = (float*)ws;
  float* ktmp = (float*)(ws + ((size_t)16 << 20));
  float* vtmp = (float*)(ws + ((size_t)24 << 20));

  const int M = B_ * S_;  // 2048 tokens
  dim3 blk(256);
  gemm_mfma_split<<<dim3(QSTRIDE / 128, M / 128), blk, 0, stream>>>(
      hidden, wq, bq, qtmp, QSTRIDE, H_);
  gemm_mfma_split<<<dim3(KSTRIDE / 128, M / 128), blk, 0, stream>>>(
      hidden, wk, bk, ktmp, KSTRIDE, H_);
  gemm_mfma_split<<<dim3(KSTRIDE / 128, M / 128), blk, 0, stream>>>(
      hidden, wv, bv, vtmp, KSTRIDE, H_);
  rope_inplace<<<dim3(S_, NH_ + NKV_, B_), dim3(64), 0, stream>>>(qtmp, ktmp,
                                                                  pos);
  attn_kernel<<<dim3(S_ / QB_, NH_, B_), blk, 0, stream>>>(qtmp, ktmp, vtmp);
  gemm_mfma_split<<<dim3(H_ / 128, M / 128), blk, 0, stream>>>(qtmp, wo, bo,
                                                               out, H_, H_);
}

// Round 7
// 777.001 us; speedup vs baseline: 4.7783x; 1.6867x over previous
//
#include <hip/hip_runtime.h>
#include <hip/hip_bf16.h>

// Problem constants
constexpr int B_ = 2, S_ = 1024, H_ = 2048;
constexpr int NH_ = 16, NKV_ = 8, HD_ = 128, GROUPS_ = 2;
constexpr int TOPK_ = 409;  // int(0.4 * 1024)
constexpr int QSTRIDE = NH_ * HD_;   // 2048
constexpr int KSTRIDE = NKV_ * HD_;  // 1024
constexpr int QB_ = 8;               // queries per attention block

typedef __attribute__((ext_vector_type(8))) short short8;
typedef __attribute__((ext_vector_type(4))) float f32x4;
typedef __attribute__((ext_vector_type(4))) unsigned u32x4;

__device__ inline unsigned fkey(float x) {
  unsigned u = __float_as_uint(x);
  return (u & 0x80000000u) ? ~u : (u | 0x80000000u);
}
__device__ inline unsigned short bf16_rne(float x) {
  unsigned u = __float_as_uint(x);
  unsigned r = u + 0x7FFFu + ((u >> 16) & 1u);
  return (unsigned short)(r >> 16);
}
__device__ inline float bf16_to_f(unsigned short h) {
  return __uint_as_float((unsigned)h << 16);
}
// float -> (hi bf16 << 16) | lo bf16   (RNE split: x ~= hi + lo)
__device__ inline unsigned packsplit(float x) {
  unsigned u = __float_as_uint(x);
  unsigned r = (u + 0x7FFFu + ((u >> 16) & 1u)) & 0xFFFF0000u;
  float rem = x - __uint_as_float(r);
  unsigned v = __float_as_uint(rem);
  unsigned l = (v + 0x7FFFu + ((v >> 16) & 1u)) >> 16;
  return r | l;
}
// 8 packed dwords (16B-aligned LDS) -> hi/lo bf16 fragments
__device__ inline void unpack8(const unsigned* p, short8& hi, short8& lo) {
  u32x4 w0 = *(const u32x4*)p;
  u32x4 w1 = *(const u32x4*)(p + 4);
  hi = short8{(short)(w0.x >> 16), (short)(w0.y >> 16), (short)(w0.z >> 16),
              (short)(w0.w >> 16), (short)(w1.x >> 16), (short)(w1.y >> 16),
              (short)(w1.z >> 16), (short)(w1.w >> 16)};
  lo = short8{(short)w0.x, (short)w0.y, (short)w0.z, (short)w0.w,
              (short)w1.x, (short)w1.y, (short)w1.z, (short)w1.w};
}

// ---------------------------------------------------------------------------
// Split-precision bf16 MFMA GEMM body: C[m,n] = sum_k A[m,k]*W[n,k] + bias[n]
// Tile: (TI*32) x 128, BK=32, 256 threads (4 waves).
// W/bias are pre-offset to this block's 128-col slice; c0 = output col base.
// ---------------------------------------------------------------------------
template <int TI>
__device__ __forceinline__ void gemm_split_body(
    const float* __restrict__ A, const float* __restrict__ W,
    const float* __restrict__ bias, float* __restrict__ C, int ldc, int c0,
    int K, int m0) {
  __shared__ unsigned short Ah[TI * 32][32];
  __shared__ unsigned short Al[TI * 32][32];
  __shared__ unsigned short Wh[128][32];
  __shared__ unsigned short Wl[128][32];
  const int tid = threadIdx.x;
  const int lane = tid & 63, wid = tid >> 6;
  const int wrow = (wid >> 1) * (TI * 16), wcol = (wid & 1) * 64;
  const int fm = lane & 15, quad = lane >> 4;
  const int srow = tid >> 3;        // 0..31
  const int skq = (tid & 7) * 4;    // 0,4,..,28
  f32x4 acc[TI][4] = {};

  for (int k0 = 0; k0 < K; k0 += 32) {
    __syncthreads();
#pragma unroll
    for (int r = 0; r < TI; ++r) {
      int row = srow + 32 * r;
      float4 av = *(const float4*)&A[(size_t)(m0 + row) * K + k0 + skq];
      unsigned short h0 = bf16_rne(av.x), h1 = bf16_rne(av.y),
                     h2 = bf16_rne(av.z), h3 = bf16_rne(av.w);
      Ah[row][skq + 0] = h0; Ah[row][skq + 1] = h1;
      Ah[row][skq + 2] = h2; Ah[row][skq + 3] = h3;
      Al[row][skq + 0] = bf16_rne(av.x - bf16_to_f(h0));
      Al[row][skq + 1] = bf16_rne(av.y - bf16_to_f(h1));
      Al[row][skq + 2] = bf16_rne(av.z - bf16_to_f(h2));
      Al[row][skq + 3] = bf16_rne(av.w - bf16_to_f(h3));
    }
#pragma unroll
    for (int r = 0; r < 4; ++r) {
      int row = srow + 32 * r;
      float4 wv2 = *(const float4*)&W[(size_t)row * K + k0 + skq];
      unsigned short g0 = bf16_rne(wv2.x), g1 = bf16_rne(wv2.y),
                     g2 = bf16_rne(wv2.z), g3 = bf16_rne(wv2.w);
      Wh[row][skq + 0] = g0; Wh[row][skq + 1] = g1;
      Wh[row][skq + 2] = g2; Wh[row][skq + 3] = g3;
      Wl[row][skq + 0] = bf16_rne(wv2.x - bf16_to_f(g0));
      Wl[row][skq + 1] = bf16_rne(wv2.y - bf16_to_f(g1));
      Wl[row][skq + 2] = bf16_rne(wv2.z - bf16_to_f(g2));
      Wl[row][skq + 3] = bf16_rne(wv2.w - bf16_to_f(g3));
    }
    __syncthreads();
    short8 ah[TI], al[TI], bh[4], bl[4];
#pragma unroll
    for (int ti = 0; ti < TI; ++ti) {
      ah[ti] = *(const short8*)&Ah[wrow + 16 * ti + fm][quad * 8];
      al[ti] = *(const short8*)&Al[wrow + 16 * ti + fm][quad * 8];
    }
#pragma unroll
    for (int tj = 0; tj < 4; ++tj) {
      bh[tj] = *(const short8*)&Wh[wcol + 16 * tj + fm][quad * 8];
      bl[tj] = *(const short8*)&Wl[wcol + 16 * tj + fm][quad * 8];
    }
#pragma unroll
    for (int ti = 0; ti < TI; ++ti)
#pragma unroll
      for (int tj = 0; tj < 4; ++tj) {
        acc[ti][tj] = __builtin_amdgcn_mfma_f32_16x16x32_bf16(
            ah[ti], bh[tj], acc[ti][tj], 0, 0, 0);
        acc[ti][tj] = __builtin_amdgcn_mfma_f32_16x16x32_bf16(
            ah[ti], bl[tj], acc[ti][tj], 0, 0, 0);
        acc[ti][tj] = __builtin_amdgcn_mfma_f32_16x16x32_bf16(
            al[ti], bh[tj], acc[ti][tj], 0, 0, 0);
      }
  }
#pragma unroll
  for (int tj = 0; tj < 4; ++tj) {
    float bsv = bias[wcol + 16 * tj + fm];
#pragma unroll
    for (int ti = 0; ti < TI; ++ti) {
      int mrow = m0 + wrow + 16 * ti + quad * 4;
      int ncol = c0 + wcol + 16 * tj + fm;
#pragma unroll
      for (int reg = 0; reg < 4; ++reg)
        C[(size_t)(mrow + reg) * ldc + ncol] = acc[ti][tj][reg] + bsv;
    }
  }
}

// Fused QKV projection: N-space = [q 0..2048) [k 2048..3072) [v 3072..4096)
__global__ __launch_bounds__(256) void gemm_qkv(
    const float* __restrict__ hidden, const float* __restrict__ wq,
    const float* __restrict__ bq, const float* __restrict__ wk,
    const float* __restrict__ bk, const float* __restrict__ wv,
    const float* __restrict__ bv, float* __restrict__ q, float* __restrict__ k,
    float* __restrict__ v) {
  const int n0 = blockIdx.x * 128, m0 = blockIdx.y * 128;
  const float* W;
  const float* bias;
  float* C;
  int ldc, c0;
  if (n0 < QSTRIDE) {
    W = wq + (size_t)n0 * H_; bias = bq + n0; C = q; ldc = QSTRIDE; c0 = n0;
  } else if (n0 < QSTRIDE + KSTRIDE) {
    int nn = n0 - QSTRIDE;
    W = wk + (size_t)nn * H_; bias = bk + nn; C = k; ldc = KSTRIDE; c0 = nn;
  } else {
    int nn = n0 - QSTRIDE - KSTRIDE;
    W = wv + (size_t)nn * H_; bias = bv + nn; C = v; ldc = KSTRIDE; c0 = nn;
  }
  gemm_split_body<4>(hidden, W, bias, C, ldc, c0, H_, m0);
}

// Generic GEMM (used for out-proj with TI=2 -> 64-row tiles, grid 512)
template <int TI>
__global__ __launch_bounds__(256) void gemm_split_k(
    const float* __restrict__ A, const float* __restrict__ W,
    const float* __restrict__ bias, float* __restrict__ C, int N, int K) {
  const int n0 = blockIdx.x * 128, m0 = blockIdx.y * (TI * 32);
  gemm_split_body<TI>(A, W + (size_t)n0 * K, bias + n0, C, N, n0, K, m0);
}

// ---------------------------------------------------------------------------
// RoPE (q,k) + split-pack q,k,v IN PLACE as (hi<<16|lo) dwords.
// grid (S, NH+2*NKV, B), block 64.
// ---------------------------------------------------------------------------
__global__ __launch_bounds__(64) void rope_pack(float* __restrict__ qtmp,
                                                float* __restrict__ ktmp,
                                                float* __restrict__ vtmp,
                                                const int* __restrict__ pos_ids) {
  const int s = blockIdx.x, hh = blockIdx.y, b = blockIdx.z;
  const int d = threadIdx.x;
  if (hh >= NH_ + NKV_) {  // v: pack only
    float* ptr = vtmp + (size_t)(b * S_ + s) * KSTRIDE + (hh - NH_ - NKV_) * HD_;
    float x = ptr[d], y = ptr[d + 64];
    unsigned* up = (unsigned*)ptr;
    up[d] = packsplit(x);
    up[d + 64] = packsplit(y);
    return;
  }
  const int pos = pos_ids[b * S_ + s];
  float* ptr = (hh < NH_)
                   ? qtmp + (size_t)(b * S_ + s) * QSTRIDE + hh * HD_
                   : ktmp + (size_t)(b * S_ + s) * KSTRIDE + (hh - NH_) * HD_;
  float x = ptr[d], y = ptr[d + 64];
  float f = (float)(1.0 / pow(1.0e6, (double)d / 64.0));
  float ang = (float)pos * f;
  float c = cosf(ang), sn = sinf(ang);
  unsigned* up = (unsigned*)ptr;
  up[d] = packsplit(x * c - y * sn);
  up[d + 64] = packsplit(y * c + x * sn);
}

// ---------------------------------------------------------------------------
// Sparse attention v4 (MFMA): one block per (b, h, 8 queries).
// QK^T and P.V via split-bf16 mfma_f32_16x16x32 (M=16: rows 0-7 queries,
// rows 8-15 duplicates, discarded). K/V/Q read as packed hi|lo dwords.
// Exact top-k via per-wave radix select on fp32 scores (unchanged semantics).
// fp32 output written in place over this block's packed-q segment.
// ---------------------------------------------------------------------------
constexpr int SCW = 1028;  // sc row stride (pad: 1024+4)

__global__ __launch_bounds__(256, 2) void attn_kernel(
    unsigned* __restrict__ qpk, const unsigned* __restrict__ kpk,
    const unsigned* __restrict__ vpk) {
  const int q0 = blockIdx.x * QB_;
  const int h = blockIdx.y, b = blockIdx.z, g = h / GROUPS_;
  const int t = threadIdx.x, lane = t & 63, wid = t >> 6;
  const int fm = lane & 15, quad = lane >> 4;

  __shared__ float sc[QB_ * SCW];      // 32.9 KB: fp32 scores -> packed probs
  __shared__ unsigned kvt[64 * 132];   // 33.8 KB: K/V tile, packed, padded
  __shared__ unsigned qst[QB_][132];   // 4.2 KB: packed q staging
  __shared__ unsigned hist[4][256];    // 4 KB
  __shared__ float redmx[4][QB_];
  __shared__ float Zsh[QB_];
  __shared__ unsigned prefix_sh[QB_];
  __shared__ unsigned selbin_sh[4];
  __shared__ int selkk_sh[4];
  const float scale = 0.08838834764831845f;  // 1/sqrt(128)

  // ---- stage packed q (8 rows x 128 dwords) ----
  {
    int qi = t >> 5, c4 = (t & 31) * 4;
    u32x4 v = *(const u32x4*)&qpk[(size_t)(b * S_ + q0 + qi) * QSTRIDE +
                                  h * HD_ + c4];
    *(u32x4*)&qst[qi][c4] = v;
  }
  __syncthreads();
  // Q A-fragments (row fm&7; rows 8-15 duplicate rows 0-7 -> discarded in C)
  short8 qh[4], ql[4];
#pragma unroll
  for (int ks = 0; ks < 4; ++ks)
    unpack8(&qst[fm & 7][ks * 32 + quad * 8], qh[ks], ql[ks]);

  // ---- QK^T over 16 tiles of 64 keys ----
  const unsigned* kg = kpk + (size_t)(b * S_) * KSTRIDE + g * HD_;
  const int kt = t >> 5, st = (t & 31) * 4;  // staging map
  f32x4 mxacc = {-1e30f, -1e30f, -1e30f, -1e30f};
  for (int tile = 0; tile < 16; ++tile) {
    __syncthreads();
#pragma unroll
    for (int j = 0; j < 8; ++j) {
      int key = kt + 8 * j;
      u32x4 w = *(const u32x4*)&kg[(size_t)(tile * 64 + key) * KSTRIDE + st];
      *(u32x4*)&kvt[key * 132 + st] = w;
    }
    __syncthreads();
    f32x4 acc = {0.f, 0.f, 0.f, 0.f};
#pragma unroll
    for (int ks = 0; ks < 4; ++ks) {
      short8 bh, bl;
      unpack8(&kvt[(wid * 16 + fm) * 132 + ks * 32 + quad * 8], bh, bl);
      acc = __builtin_amdgcn_mfma_f32_16x16x32_bf16(qh[ks], bh, acc, 0, 0, 0);
      acc = __builtin_amdgcn_mfma_f32_16x16x32_bf16(qh[ks], bl, acc, 0, 0, 0);
      acc = __builtin_amdgcn_mfma_f32_16x16x32_bf16(ql[ks], bh, acc, 0, 0, 0);
    }
    // C/D: col = fm (key within wave's 16), row = quad*4+reg (rows 0-7 valid)
    if (quad < 2) {
      int key = tile * 64 + wid * 16 + fm;
#pragma unroll
      for (int reg = 0; reg < 4; ++reg) {
        float sval = acc[reg] * scale;
        sc[(quad * 4 + reg) * SCW + key] = sval;
        mxacc[reg] = fmaxf(mxacc[reg], sval);
      }
    }
  }
  // per-wave row max: reduce across fm lanes (quad bits untouched)
#pragma unroll
  for (int o = 1; o < 16; o <<= 1) {
    mxacc[0] = fmaxf(mxacc[0], __shfl_xor(mxacc[0], o));
    mxacc[1] = fmaxf(mxacc[1], __shfl_xor(mxacc[1], o));
    mxacc[2] = fmaxf(mxacc[2], __shfl_xor(mxacc[2], o));
    mxacc[3] = fmaxf(mxacc[3], __shfl_xor(mxacc[3], o));
  }
  if (fm == 0 && quad < 2) {
#pragma unroll
    for (int reg = 0; reg < 4; ++reg) redmx[wid][quad * 4 + reg] = mxacc[reg];
  }

  // ---- per-wave radix select: wave wid -> queries 2*wid, 2*wid+1 ----
  for (int sq = 0; sq < 2; ++sq) {
    const int qi = wid * 2 + sq;
    int kk = TOPK_;
    unsigned prefix = 0;
    for (int pass = 0; pass < 4; ++pass) {
      const int shift = 24 - 8 * pass;
      const unsigned pmask = pass ? (0xFFFFFFFFu << (shift + 8)) : 0u;
      *(u32x4*)&hist[wid][4 * lane] = (u32x4){0, 0, 0, 0};
      __syncthreads();
#pragma unroll 4
      for (int j = 0; j < 16; ++j) {
        unsigned u = fkey(sc[qi * SCW + lane + 64 * j]);
        if ((u & pmask) == (prefix & pmask))
          atomicAdd(&hist[wid][(u >> shift) & 255], 1u);
      }
      __syncthreads();
      u32x4 cw = *(const u32x4*)&hist[wid][4 * lane];
      int c0 = (int)cw.x, c1 = (int)cw.y, c2 = (int)cw.z, c3 = (int)cw.w;
      int s3 = c3, s2 = c2 + s3, s1 = c1 + s2, s0 = c0 + s1;
      int tot = s0;
      int suf = tot;
#pragma unroll
      for (int off = 1; off < 64; off <<= 1) {
        int vv = __shfl_down(suf, off);
        if (lane + off < 64) suf += vv;
      }
      int above_lanes = suf - tot;
      int i0 = s0 + above_lanes, i1 = s1 + above_lanes;
      int i2 = s2 + above_lanes, i3 = s3 + above_lanes;
      if (i3 >= kk && i3 - c3 < kk) {
        selbin_sh[wid] = (unsigned)(4 * lane + 3); selkk_sh[wid] = kk - (i3 - c3);
      }
      if (i2 >= kk && i2 - c2 < kk) {
        selbin_sh[wid] = (unsigned)(4 * lane + 2); selkk_sh[wid] = kk - (i2 - c2);
      }
      if (i1 >= kk && i1 - c1 < kk) {
        selbin_sh[wid] = (unsigned)(4 * lane + 1); selkk_sh[wid] = kk - (i1 - c1);
      }
      if (i0 >= kk && i0 - c0 < kk) {
        selbin_sh[wid] = (unsigned)(4 * lane + 0); selkk_sh[wid] = kk - (i0 - c0);
      }
      __syncthreads();
      prefix |= selbin_sh[wid] << shift;
      kk = selkk_sh[wid];
    }
    if (lane == 0) prefix_sh[qi] = prefix;
  }
  __syncthreads();

  // ---- masked softmax numerators; pack P in place as hi|lo dwords ----
  {
    const int qi = t >> 5, li = t & 31;
    const float mx = fmaxf(fmaxf(redmx[0][qi], redmx[1][qi]),
                           fmaxf(redmx[2][qi], redmx[3][qi]));
    const unsigned pref = prefix_sh[qi];
    unsigned* scp = (unsigned*)&sc[qi * SCW];
    float zloc = 0.f;
#pragma unroll 8
    for (int j = 0; j < 32; ++j) {
      int i = li + 32 * j;
      float s = sc[qi * SCW + i];
      float p = (fkey(s) >= pref) ? __expf(s - mx) : 0.0f;
      zloc += p;
      scp[i] = packsplit(p);
    }
#pragma unroll
    for (int off = 1; off < 32; off <<= 1) zloc += __shfl_xor(zloc, off);
    if (li == 0) Zsh[qi] = zloc;
  }

  // ---- P.V over 16 tiles of 64 keys (V staged packed, same layout as K) ----
  const unsigned* vg = vpk + (size_t)(b * S_) * KSTRIDE + g * HD_;
  f32x4 oacc[2] = {{0.f, 0.f, 0.f, 0.f}, {0.f, 0.f, 0.f, 0.f}};
  for (int tile = 0; tile < 16; ++tile) {
    __syncthreads();
#pragma unroll
    for (int j = 0; j < 8; ++j) {
      int key = kt + 8 * j;
      u32x4 w = *(const u32x4*)&vg[(size_t)(tile * 64 + key) * KSTRIDE + st];
      *(u32x4*)&kvt[key * 132 + st] = w;
    }
    __syncthreads();
#pragma unroll
    for (int ks = 0; ks < 2; ++ks) {
      short8 ph, pl;
      unpack8((const unsigned*)&sc[(fm & 7) * SCW + tile * 64 + ks * 32 +
                                   quad * 8],
              ph, pl);
#pragma unroll
      for (int ns = 0; ns < 2; ++ns) {
        const int dim = wid * 32 + ns * 16 + fm;
        unsigned w0 = kvt[(ks * 32 + quad * 8 + 0) * 132 + dim];
        unsigned w1 = kvt[(ks * 32 + quad * 8 + 1) * 132 + dim];
        unsigned w2 = kvt[(ks * 32 + quad * 8 + 2) * 132 + dim];
        unsigned w3 = kvt[(ks * 32 + quad * 8 + 3) * 132 + dim];
        unsigned w4 = kvt[(ks * 32 + quad * 8 + 4) * 132 + dim];
        unsigned w5 = kvt[(ks * 32 + quad * 8 + 5) * 132 + dim];
        unsigned w6 = kvt[(ks * 32 + quad * 8 + 6) * 132 + dim];
        unsigned w7 = kvt[(ks * 32 + quad * 8 + 7) * 132 + dim];
        short8 vh = short8{(short)(w0 >> 16), (short)(w1 >> 16),
                           (short)(w2 >> 16), (short)(w3 >> 16),
                           (short)(w4 >> 16), (short)(w5 >> 16),
                           (short)(w6 >> 16), (short)(w7 >> 16)};
        short8 vl = short8{(short)w0, (short)w1, (short)w2, (short)w3,
                           (short)w4, (short)w5, (short)w6, (short)w7};
        oacc[ns] =
            __builtin_amdgcn_mfma_f32_16x16x32_bf16(ph, vh, oacc[ns], 0, 0, 0);
        oacc[ns] =
            __builtin_amdgcn_mfma_f32_16x16x32_bf16(ph, vl, oacc[ns], 0, 0, 0);
        oacc[ns] =
            __builtin_amdgcn_mfma_f32_16x16x32_bf16(pl, vh, oacc[ns], 0, 0, 0);
      }
    }
  }

  // ---- epilogue: rows quad*4+reg (quad<2), col wid*32+ns*16+fm ----
  if (quad < 2) {
#pragma unroll
    for (int reg = 0; reg < 4; ++reg) {
      const int q = quad * 4 + reg;
      const float invZ = 1.0f / Zsh[q];  // Z >= 1 structurally
      float* outp = (float*)qpk +
                    (size_t)(b * S_ + q0 + q) * QSTRIDE + h * HD_ + wid * 32;
#pragma unroll
      for (int ns = 0; ns < 2; ++ns)
        outp[ns * 16 + fm] = oacc[ns][reg] * invZ;
    }
  }
}

// ---------------------------------------------------------------------------
extern "C" void kernel_launch(void* const* d_in, const int* in_sizes, int n_in,
                              void* d_out, int out_size, void* d_ws,
                              size_t ws_size, hipStream_t stream) {
  // All tensors are float32 per the reference; position_ids is int32.
  const float* hidden = (const float*)d_in[0];
  const float* wq = (const float*)d_in[1];
  const float* bq = (const float*)d_in[2];
  const float* wk = (const float*)d_in[3];
  const float* bk = (const float*)d_in[4];
  const float* wv = (const float*)d_in[5];
  const float* bv = (const float*)d_in[6];
  const float* wo = (const float*)d_in[7];
  const float* bo = (const float*)d_in[8];
  const int* pos = (const int*)d_in[9];
  float* out = (float*)d_out;

  char* ws = (char*)d_ws;
  // ws layout: qtmp 16MB | ktmp 8MB | vtmp 8MB = 32MB.
  // After rope_pack, all three hold packed (hi|lo) dwords in place.
  // attn writes fp32 output in place over its own q segment.
  float* qtmp = (float*)ws;
  float* ktmp = (float*)(ws + ((size_t)16 << 20));
  float* vtmp = (float*)(ws + ((size_t)24 << 20));

  dim3 blk(256);
  // Fused QKV projection: grid 32x16 = 512 blocks (2/CU)
  gemm_qkv<<<dim3(32, 16), blk, 0, stream>>>(hidden, wq, bq, wk, bk, wv, bv,
                                             qtmp, ktmp, vtmp);
  // RoPE + in-place split-pack of q, k, v
  rope_pack<<<dim3(S_, NH_ + 2 * NKV_, B_), dim3(64), 0, stream>>>(qtmp, ktmp,
                                                                   vtmp, pos);
  // MFMA sparse attention
  attn_kernel<<<dim3(S_ / QB_, NH_, B_), blk, 0, stream>>>(
      (unsigned*)qtmp, (const unsigned*)ktmp, (const unsigned*)vtmp);
  // Output projection: 64-row tiles -> grid 16x32 = 512 blocks (2/CU)
  gemm_split_k<2><<<dim3(H_ / 128, (B_ * S_) / 64), blk, 0, stream>>>(
      qtmp, wo, bo, out, H_, H_);
}